// Round 1
// baseline (52.553 us; speedup 1.0000x reference)
//
#include <hip/hip_runtime.h>

// CombinePatches: col2im/fold of 4x4x4 stride-2 volume patches + divide by
// overlap count. Gather formulation: each output voxel (b,d,h,w,c) sums the
// <=8 patch elements that scatter onto it (kernel offset i must satisfy
// i ≡ d (mod 2), 0 <= (d-i)/2 < od; same for h,w). Count = #valid combos,
// always in {1,2,4,8} -> exact fp32 reciprocal.

constexpr int Bsz = 2;
constexpr int Dd  = 64;
constexpr int Hh  = 128;
constexpr int Ww  = 128;
// C = 4 floats -> one float4 per voxel
constexpr int OD = 31;
constexpr int OH = 63;
constexpr int OW = 63;
// patch inner layout: [kd,kh,kw,C] -> float4 offset = i*16 + j*4 + l, 64 float4/patch

__global__ __launch_bounds__(256) void fold_gather_kernel(
    const float4* __restrict__ p, float4* __restrict__ out)
{
    int n = blockIdx.x * 256 + threadIdx.x;      // one thread per (b,d,h,w)
    // total = 2*64*128*128 = 2^21, grid sized exactly
    int w = n & (Ww - 1);
    int h = (n >> 7) & (Hh - 1);
    int d = (n >> 14) & (Dd - 1);
    int b = n >> 20;

    int i0 = d & 1, j0 = h & 1, l0 = w & 1;

    float4 acc = make_float4(0.f, 0.f, 0.f, 0.f);
    int cnt = 0;

    #pragma unroll
    for (int ii = 0; ii < 2; ++ii) {
        int i  = i0 + 2 * ii;
        int zd = (d - i) >> 1;                   // d-i is even by construction
        if ((unsigned)zd >= (unsigned)OD) continue;
        #pragma unroll
        for (int jj = 0; jj < 2; ++jj) {
            int j  = j0 + 2 * jj;
            int zh = (h - j) >> 1;
            if ((unsigned)zh >= (unsigned)OH) continue;
            #pragma unroll
            for (int ll = 0; ll < 2; ++ll) {
                int l  = l0 + 2 * ll;
                int zw = (w - l) >> 1;
                if ((unsigned)zw >= (unsigned)OW) continue;
                // patch float4 index: (((b*OD+zd)*OH+zh)*OW+zw)*64 + i*16+j*4+l
                int pidx = ((((b * OD + zd) * OH + zh) * OW + zw) << 6)
                           + (i << 4) + (j << 2) + l;   // max ~15.7M, fits int
                float4 v = p[pidx];
                acc.x += v.x; acc.y += v.y; acc.z += v.z; acc.w += v.w;
                ++cnt;
            }
        }
    }

    float inv = 1.0f / (float)cnt;               // cnt in {1,2,4,8}: exact
    acc.x *= inv; acc.y *= inv; acc.z *= inv; acc.w *= inv;
    out[n] = acc;
}

extern "C" void kernel_launch(void* const* d_in, const int* in_sizes, int n_in,
                              void* d_out, int out_size, void* d_ws, size_t ws_size,
                              hipStream_t stream)
{
    const float4* patches = (const float4*)d_in[0];   // [2,31,63,63,256] f32
    // d_in[1] ("inputs") is only used for its shape in the reference.
    float4* out = (float4*)d_out;                     // [2,64,128,128,4] f32

    const int total = Bsz * Dd * Hh * Ww;             // 2^21 threads
    fold_gather_kernel<<<total / 256, 256, 0, stream>>>(patches, out);
}